// Round 1
// baseline (169.157 us; speedup 1.0000x reference)
//
#include <hip/hip_runtime.h>

// BCELoss(reduce=False) with "already-correct → 0" masking, element-wise over N fp32.
// Memory-bound: 2 loads + 1 store per element. float4 vectorization, 16 B/lane.

__device__ __forceinline__ float bce1(float p, float y) {
    float log_p   = fmaxf(logf(p),     -100.0f);   // torch clamps log at -100
    float log_1mp = fmaxf(log1pf(-p),  -100.0f);
    float loss = -(y * log_p + (1.0f - y) * log_1mp);
    // zero out where prediction already on correct side of 0.5
    bool correct = (p - 0.5f) * (2.0f * y - 1.0f) > 0.0f;
    return correct ? 0.0f : loss;
}

__global__ void __launch_bounds__(256)
bce_loss_kernel(const float4* __restrict__ p4,
                const float4* __restrict__ y4,
                float4* __restrict__ o4,
                int n4,
                const float* __restrict__ p_s,
                const float* __restrict__ y_s,
                float* __restrict__ o_s,
                int n) {
    int i = blockIdx.x * blockDim.x + threadIdx.x;
    if (i < n4) {
        float4 p = p4[i];
        float4 y = y4[i];
        float4 o;
        o.x = bce1(p.x, y.x);
        o.y = bce1(p.y, y.y);
        o.z = bce1(p.z, y.z);
        o.w = bce1(p.w, y.w);
        o4[i] = o;
    }
    // scalar tail (n % 4 elements) — N=2^24 means this is normally empty
    if (i == 0) {
        for (int j = n4 * 4; j < n; ++j) {
            o_s[j] = bce1(p_s[j], y_s[j]);
        }
    }
}

extern "C" void kernel_launch(void* const* d_in, const int* in_sizes, int n_in,
                              void* d_out, int out_size, void* d_ws, size_t ws_size,
                              hipStream_t stream) {
    const float* y_pred   = (const float*)d_in[0];
    const float* y_actual = (const float*)d_in[1];
    float* out = (float*)d_out;
    int n  = in_sizes[0];
    int n4 = n >> 2;

    const int block = 256;
    int grid = (n4 + block - 1) / block;
    bce_loss_kernel<<<grid, block, 0, stream>>>(
        (const float4*)y_pred, (const float4*)y_actual, (float4*)out, n4,
        y_pred, y_actual, out, n);
}

// Round 2
// 166.054 us; speedup vs baseline: 1.0187x; 1.0187x over previous
//
#include <hip/hip_runtime.h>

// BCELoss(reduce=False) + "already-correct -> 0" masking, N fp32 elements.
// Key simplification: y_actual is binary {0.0, 1.0}, so
//   q    = (y==1) ? p : 1-p
//   loss = (q > 0.5) ? 0 : -max(log(q), -100)
// One hardware log (v_log_f32, log2) per element instead of logf+log1pf
// software polynomials. R0 was VALU-bound (VALUBusy 88%, HBM 25%).

__device__ __forceinline__ float bce1(float p, float y) {
    float q = (y == 1.0f) ? p : (1.0f - p);
    // v_log_f32: log2(q); convert to natural log via *ln2
    float lg = __builtin_amdgcn_logf(q) * 0.6931471805599453f;
    float ll = fmaxf(lg, -100.0f);      // torch clamp (inert for q >= 1e-4)
    return (q > 0.5f) ? 0.0f : -ll;
}

__global__ void __launch_bounds__(256)
bce_loss_kernel(const float4* __restrict__ p4,
                const float4* __restrict__ y4,
                float4* __restrict__ o4,
                int n4,
                const float* __restrict__ p_s,
                const float* __restrict__ y_s,
                float* __restrict__ o_s,
                int n) {
    int i = blockIdx.x * blockDim.x + threadIdx.x;
    if (i < n4) {
        float4 p = p4[i];
        float4 y = y4[i];
        float4 o;
        o.x = bce1(p.x, y.x);
        o.y = bce1(p.y, y.y);
        o.z = bce1(p.z, y.z);
        o.w = bce1(p.w, y.w);
        o4[i] = o;
    }
    // scalar tail (n % 4) — empty for N = 2^24
    if (i == 0) {
        for (int j = n4 * 4; j < n; ++j) {
            o_s[j] = bce1(p_s[j], y_s[j]);
        }
    }
}

extern "C" void kernel_launch(void* const* d_in, const int* in_sizes, int n_in,
                              void* d_out, int out_size, void* d_ws, size_t ws_size,
                              hipStream_t stream) {
    const float* y_pred   = (const float*)d_in[0];
    const float* y_actual = (const float*)d_in[1];
    float* out = (float*)d_out;
    int n  = in_sizes[0];
    int n4 = n >> 2;

    const int block = 256;
    int grid = (n4 + block - 1) / block;
    bce_loss_kernel<<<grid, block, 0, stream>>>(
        (const float4*)y_pred, (const float4*)y_actual, (float4*)out, n4,
        y_pred, y_actual, out, n);
}